// Round 3
// baseline (187.639 us; speedup 1.0000x reference)
//
#include <hip/hip_runtime.h>
#include <stdint.h>

typedef uint32_t u32;
typedef uint64_t u64;

// BinaryNet on MI355X: everything after binarize() is {-1,0,+1}.
// Layer1 (9 taps, odd) -> exact +-1 per output -> 1 bit.
// Layer2 (36 taps, even) -> ternary -> (value bit, nonzero bit).
// All convs/FCs computed as XOR + popcount on packed sign bits.
//
// R8: float4 staging + bit-spread transpose. Iteration-budget arithmetic
// (185.6us total - 68.5us ws-poison fill - tiny reset fills) puts binnet at
// ~70-95us, 4-5x its 18.7us HBM floor, and explains why R6's launch-shape
// change was null: a latency-serialized staging chain (load -> ~900cy wait ->
// ballot, per word) has wall time ~225x900cy per wave no matter how many
// waves run concurrently. Fix: 4x fewer serialization points. Lane l loads
// the float4 at chunk-offset 4l (16B/lane, 1KB per wave-instruction, 57 loads
// instead of 225). The 4 ballots per 256-float chunk produce a PERMUTED bit
// layout (stP[4T+c] bit l = sign(float 256T+4l+c)); a cooperative transpose
// rebuilds flat sign words via the fixed bit-spread i->4i:
//   flat(w) bit j = stP[4(w>>2) + (j&3)] bit (16(w&3) + (j>>2))
// Each lane reconstructs ~3.5 of the 224 flat words (~400 VALU total) into
// stF; the tail 64 floats (14336..14399) are balloted directly as flat word
// 224. Everything downstream of Wd[i]=stF[w0+i] is byte-identical to the
// verified eval. Weight packing (R7 ballot-gather, verified) moves after the
// transpose so its ~87 live VGPRs never overlap the 56-VGPR staging batch.
//
// Launch: <<<B/64, 64>>>, __launch_bounds__(64,2) -> 128 VGPR budget,
// 8 one-wave blocks/CU. Staging batch = 14 float4 = 56 live VGPRs.
//
// Discriminating experiment: if staging was latency-serialized, binnet drops
// ~40-60us (total ~135-155). If it was already BW-bound, total is unchanged
// +-3us and the controllable region is confirmed at its floor.
//
// Bit-layout reference (identical target semantics as prior rounds):
//   w1p[c]  : 9-bit,  bit 3*ky+kx
//   W2[d]   : 36-bit, bit 12*ky+4*kx+c
//   W3L[e]  : 64-bit, bit 8*(3*ky+kx)+d  (taps 0..7)
//   W3H[e]  : 8-bit,  bit d              (tap 8)
//   WF1[j]  : 16-bit, bit e
//   wf2     : 8-bit,  bit j

__device__ __forceinline__ u64 spread4(u64 x) {
  // bit i (0..15) -> bit 4i
  x &= 0xFFFFull;
  x = (x | (x << 24)) & 0x000000FF000000FFull;
  x = (x | (x << 12)) & 0x000F000F000F000Full;
  x = (x | (x <<  6)) & 0x0303030303030303ull;
  x = (x | (x <<  3)) & 0x1111111111111111ull;
  return x;
}

__device__ __forceinline__ u64 flat_from(const u64* stP, int w) {
  const int t4 = (w >> 2) << 2;
  const int q = (w & 3) * 16;
  return  spread4(stP[t4 + 0] >> q)
       | (spread4(stP[t4 + 1] >> q) << 1)
       | (spread4(stP[t4 + 2] >> q) << 2)
       | (spread4(stP[t4 + 3] >> q) << 3);
}

__global__ __launch_bounds__(64, 2) void binnet(const float* __restrict__ x,
                                                const float* __restrict__ w1,
                                                const float* __restrict__ w2,
                                                const float* __restrict__ w3,
                                                const float* __restrict__ wfc1,
                                                const float* __restrict__ wfc2,
                                                float* __restrict__ out) {
  __shared__ u64 stP[224];   // permuted ballot words, 56 chunks x 4
  __shared__ u64 stF[228];   // flat sign words 0..224 + zero tail
  const int lane = threadIdx.x;       // one wave per block
  const int b0 = blockIdx.x * 64;     // this block's 64 samples

  // ---- Stage: 56 chunks of 256 floats, lane l takes float4 at 4l ----
  const float* xw = x + (size_t)b0 * 225;
  const float4* xq = (const float4*)xw;
  if (lane < 3) stF[225 + lane] = 0;  // zero pad for Wd overrun
  #pragma unroll
  for (int g = 0; g < 4; ++g) {
    float4 v[14];
    #pragma unroll
    for (int k = 0; k < 14; ++k) v[k] = xq[(g * 14 + k) * 64 + lane];
    #pragma unroll
    for (int k = 0; k < 14; ++k) {
      const int T = g * 14 + k;
      const u64 m0 = __ballot(v[k].x < 0.f);
      const u64 m1 = __ballot(v[k].y < 0.f);
      const u64 m2 = __ballot(v[k].z < 0.f);
      const u64 m3 = __ballot(v[k].w < 0.f);
      if (lane == 0) {
        stP[4 * T + 0] = m0; stP[4 * T + 1] = m1;
        stP[4 * T + 2] = m2; stP[4 * T + 3] = m3;
      }
    }
  }
  {  // tail: floats 14336..14399 -> flat word 224 directly
    const float tv = xw[14336 + lane];
    const u64 m = __ballot(tv < 0.f);
    if (lane == 0) stF[224] = m;
  }
  __syncthreads();

  // ---- Cooperative transpose: 224 flat words, ~3.5 per lane ----
  #pragma unroll
  for (int k = 0; k < 3; ++k) {
    const int w = lane + 64 * k;
    stF[w] = flat_from(stP, w);
  }
  if (lane < 32) {
    const int w = 192 + lane;
    stF[w] = flat_from(stP, w);
  }
  __syncthreads();

  // ---- Weight packing via inverse-permuted sign ballots (R7, verified) ----
  const float vw1 = w1[lane < 36 ? lane : 0];
  const u64 m1 = __ballot((lane < 36) && (vw1 < 0.f));
  const u32 w1p0 = (u32)(m1      ) & 0x1FFu;
  const u32 w1p1 = (u32)(m1 >>  9) & 0x1FFu;
  const u32 w1p2 = (u32)(m1 >> 18) & 0x1FFu;
  const u32 w1p3 = (u32)(m1 >> 27) & 0x1FFu;

  const int w2i = (lane < 36) ? ((lane & 3) * 9 + (lane >> 2)) : 0;
  u64 W2[8];
  #pragma unroll
  for (int d = 0; d < 8; ++d) {
    const float v = w2[d * 36 + w2i];
    W2[d] = __ballot((lane < 36) && (v < 0.f));   // bits >=36 are 0
  }

  const int w3i = (lane & 7) * 9 + (lane >> 3);
  u64 W3L[16];
  u32 W3H[16];
  #pragma unroll
  for (int e = 0; e < 16; ++e) W3L[e] = __ballot(w3[e * 72 + w3i] < 0.f);
  {
    const int hb = (lane & 7) * 9 + 8;
    const u64 h0 = __ballot(w3[((lane >> 3)    ) * 72 + hb] < 0.f);
    const u64 h1 = __ballot(w3[((lane >> 3) + 8) * 72 + hb] < 0.f);
    #pragma unroll
    for (int e = 0; e < 16; ++e)
      W3H[e] = (u32)(((e < 8 ? h0 : h1) >> (8 * (e & 7))) & 0xFFu);
  }

  const u64 f0b = __ballot(wfc1[lane] < 0.f);
  const u64 f1b = __ballot(wfc1[64 + lane] < 0.f);
  u32 WF1[8];
  #pragma unroll
  for (int j = 0; j < 8; ++j)
    WF1[j] = (u32)(((j < 4 ? f0b : f1b) >> (16 * (j & 3))) & 0xFFFFu);

  const float vf2 = wfc2[lane < 8 ? lane : 0];
  const u32 wf2 = (u32)__ballot((lane < 8) && (vf2 < 0.f)) & 0xFFu;

  // ---- Eval: byte-identical to the verified kernel ----
  const u64* stw = stF;
  const int f0i = 225 * lane;
  const int w0 = f0i >> 6;
  const int sh = f0i & 63;
  u64 Wd[5];
  #pragma unroll
  for (int i = 0; i < 5; ++i) Wd[i] = stw[w0 + i];
  u64 Bv[4];
  #pragma unroll
  for (int i = 0; i < 4; ++i)
    Bv[i] = (Wd[i] >> sh) | ((Wd[i + 1] << (63 - sh)) << 1);  // sh==0 -> 0 contribution

  // rows: rb[r] bit k = sign(x[b,0,r,k])
  u32 rb[15];
  #pragma unroll
  for (int r = 0; r < 15; ++r) {
    const int f = 15 * r, w = f >> 6, o = f & 63;
    u64 v = Bv[w] >> o;
    if (o > 49) v |= Bv[w + 1] << (64 - o);
    rb[r] = (u32)v & 0x7FFFu;
  }

  // ---- Layer 1: 4ch, 15x15 -> 7x7, 9 taps (always +-1 out) ----
  u64 a1[4] = {0, 0, 0, 0};  // bit 4*(7*oy+ox)+c, 1 = negative
  int pix = 0;
  #pragma unroll
  for (int oy = 0; oy < 7; ++oy) {
    const u32 r0 = rb[2 * oy], r1 = rb[2 * oy + 1], r2 = rb[2 * oy + 2];
    #pragma unroll
    for (int ox = 0; ox < 7; ++ox) {
      const u32 t9 = ((r0 >> (2 * ox)) & 7) | (((r1 >> (2 * ox)) & 7) << 3)
                   | (((r2 >> (2 * ox)) & 7) << 6);
      u32 nib = 0;
      nib |= (u32)(__popc(t9 ^ w1p0) >= 5) << 0;
      nib |= (u32)(__popc(t9 ^ w1p1) >= 5) << 1;
      nib |= (u32)(__popc(t9 ^ w1p2) >= 5) << 2;
      nib |= (u32)(__popc(t9 ^ w1p3) >= 5) << 3;
      a1[pix >> 4] |= (u64)nib << ((pix & 15) * 4);
      ++pix;
    }
  }

  // ---- Layer 2: 8ch, 7x7 -> 3x3, 36 taps (ternary out) ----
  u64 v2lo = 0, nz2lo = 0; u32 v2hi = 0, nz2hi = 0;  // bit 8*(3*oy+ox)+d
  #pragma unroll
  for (int oy = 0; oy < 3; ++oy) {
    #pragma unroll
    for (int ox = 0; ox < 3; ++ox) {
      u64 T = 0;
      #pragma unroll
      for (int ky = 0; ky < 3; ++ky) {
        const int p = 4 * (7 * (2 * oy + ky) + 2 * ox);
        const int w = p >> 6, o = p & 63;
        u64 v = a1[w] >> o;
        if (o > 52) v |= a1[w + 1] << (64 - o);
        T |= (v & 0xFFFull) << (12 * ky);
      }
      const int pix2 = 3 * oy + ox;
      u32 bv = 0, bz = 0;
      #pragma unroll
      for (int d = 0; d < 8; ++d) {
        const int cnt = __popcll(T ^ W2[d]);  // #neg products of 36
        bv |= (u32)(cnt > 18) << d;           // sum = 36-2cnt < 0
        bz |= (u32)(cnt != 18) << d;          // nonzero
      }
      if (pix2 < 8) { v2lo |= (u64)bv << (8 * pix2); nz2lo |= (u64)bz << (8 * pix2); }
      else          { v2hi = bv; nz2hi = bz; }
    }
  }

  // ---- Layer 3: 16ch, 3x3 -> 1x1, 72 taps, ternary in/out ----
  const int nztot = __popcll(nz2lo) + __popc(nz2hi);
  u32 s3v = 0, s3nz = 0;
  #pragma unroll
  for (int e = 0; e < 16; ++e) {
    const int cnt = __popcll(nz2lo & (v2lo ^ W3L[e])) + __popc(nz2hi & (v2hi ^ W3H[e]));
    const int s = nztot - 2 * cnt;
    s3v  |= (u32)(s < 0) << e;
    s3nz |= (u32)(s != 0) << e;
  }

  // ---- FC1: 16 -> 8, ternary ----
  const int n3 = __popc(s3nz);
  u32 hv = 0, hz = 0;
  #pragma unroll
  for (int j = 0; j < 8; ++j) {
    const int c2 = __popc(s3nz & (s3v ^ WF1[j]));
    const int s = n3 - 2 * c2;
    hv |= (u32)(s < 0) << j;
    hz |= (u32)(s != 0) << j;
  }

  // ---- FC2: 8 -> 1 (no hardtanh) ----
  const int c3 = __popc(hz & (hv ^ wf2));
  const int sfin = __popc(hz) - 2 * c3;
  out[b0 + lane] = (float)sfin;
}

extern "C" void kernel_launch(void* const* d_in, const int* in_sizes, int n_in,
                              void* d_out, int out_size, void* d_ws, size_t ws_size,
                              hipStream_t stream) {
  const float* x    = (const float*)d_in[0];
  const float* w1   = (const float*)d_in[1];
  const float* w2   = (const float*)d_in[2];
  const float* w3   = (const float*)d_in[3];
  const float* wfc1 = (const float*)d_in[4];
  const float* wfc2 = (const float*)d_in[5];
  float* out = (float*)d_out;
  const int B = in_sizes[0] / 225;  // 131072

  (void)d_ws; (void)ws_size; (void)n_in; (void)out_size;
  binnet<<<B / 64, 64, 0, stream>>>(x, w1, w2, w3, wfc1, wfc2, out);
}

// Round 4
// 185.396 us; speedup vs baseline: 1.0121x; 1.0121x over previous
//
#include <hip/hip_runtime.h>
#include <stdint.h>

typedef uint32_t u32;
typedef uint64_t u64;

// BinaryNet on MI355X: everything after binarize() is {-1,0,+1}.
// Layer1 (9 taps, odd) -> exact +-1 per output -> 1 bit.
// Layer2 (36 taps, even) -> ternary -> (value bit, nonzero bit).
// All convs/FCs computed as XOR + popcount on packed sign bits.
//
// R9 = revert to the verified R7 kernel (best measured: 185.6 us).
// Evidence trail:
//  - R6 (4x more blocks, 1 wave/block): null -> not occupancy/phase-bound.
//  - R8 (float4 staging, 4x fewer load rounds + bit-spread transpose): null
//    (+2 us = added transpose VALU) -> staging is NOT latency-serialized.
//  - In-flight arithmetic: 8 waves/CU x 45 outstanding 256B wave-loads
//    ~ 117 KB/CU in flight vs ~9 KB needed to saturate 6.3 TB/s at 900 cy
//    -> staging achieves near-peak BW as-is.
// binnet ~ 20-25 us vs its 18.7 us mandatory-read floor (118 MB of f32
// signs); the rest of the timed window is harness-owned (one 472 MB
// ws-poison fill ~68 us + dozens of tiny reset fills). This kernel is at
// the controllable roofline.
//
// Single-kernel design (R7): weight packing is done in-kernel via
// inverse-permuted ballot-gather (each lane loads the weight element whose
// TARGET bit position equals its lane index; one __ballot per packed word),
// placed AFTER the x-staging loop so the 45-deep load batch (~56 live VGPRs)
// and the ~87 weight VGPRs are never simultaneously live.
// Launch: <<<B/64, 64>>>, __launch_bounds__(64,2) -> full 128-VGPR budget at
// the grid's natural 2 waves/SIMD; 8 independent 1-wave blocks/CU.
//
// Bit-layout reference:
//   w1p[c]  : 9-bit,  bit 3*ky+kx
//   W2[d]   : 36-bit, bit 12*ky+4*kx+c
//   W3L[e]  : 64-bit, bit 8*(3*ky+kx)+d  (taps 0..7)
//   W3H[e]  : 8-bit,  bit d              (tap 8)
//   WF1[j]  : 16-bit, bit e
//   wf2     : 8-bit,  bit j

__global__ __launch_bounds__(64, 2) void binnet(const float* __restrict__ x,
                                                const float* __restrict__ w1,
                                                const float* __restrict__ w2,
                                                const float* __restrict__ w3,
                                                const float* __restrict__ wfc1,
                                                const float* __restrict__ wfc2,
                                                float* __restrict__ out) {
  __shared__ u64 st[228];
  const int lane = threadIdx.x;       // one wave per block
  const int b0 = blockIdx.x * 64;     // this block's 64 samples

  // ---- Stage this wave's 64 samples' 225 sign words (flat float order) ----
  // word t = ballot over lanes of float [b0*225 + 64t + lane].
  // 5 groups of 45: all 45 coalesced loads issue before the ballot/store
  // drain (45 live floats ~ 55 VGPRs).
  const float* xw = x + (size_t)b0 * 225 + lane;
  if (lane < 3) st[225 + lane] = 0;   // zero tail words
  #pragma unroll
  for (int g = 0; g < 5; ++g) {
    float v[45];
    #pragma unroll
    for (int k = 0; k < 45; ++k) v[k] = xw[(g * 45 + k) * 64];
    #pragma unroll
    for (int k = 0; k < 45; ++k) {
      const u64 m = __ballot(v[k] < 0.f);
      if (lane == 0) st[g * 45 + k] = m;
    }
  }

  // ---- Weight packing via inverse-permuted sign ballots ----
  // w1 [4][9]: memory order c*9+k == bit order 9c+k. One ballot.
  const float vw1 = w1[lane < 36 ? lane : 0];
  const u64 m1 = __ballot((lane < 36) && (vw1 < 0.f));
  const u32 w1p0 = (u32)(m1      ) & 0x1FFu;
  const u32 w1p1 = (u32)(m1 >>  9) & 0x1FFu;
  const u32 w1p2 = (u32)(m1 >> 18) & 0x1FFu;
  const u32 w1p3 = (u32)(m1 >> 27) & 0x1FFu;

  // w2 [8][4][3][3]: target bit bp = 4t+c (t=3ky+kx) <- mem d*36 + c*9 + t.
  // Lane bp loads (bp&3)*9 + (bp>>2); lanes >=36 clamped + predicated off.
  const int w2i = (lane < 36) ? ((lane & 3) * 9 + (lane >> 2)) : 0;
  u64 W2[8];
  #pragma unroll
  for (int d = 0; d < 8; ++d) {
    const float v = w2[d * 36 + w2i];
    W2[d] = __ballot((lane < 36) && (v < 0.f));   // bits >=36 are 0
  }

  // w3 [16][8][3][3]: target bit bp = 8t+d <- mem e*72 + d*9 + t.
  // Lo (t=0..7): lane l loads e*72 + (l&7)*9 + (l>>3)  -> bit l = 8t+d.
  // Hi (t=8): two combined ballots, 8 channels' bit-d bytes per ballot.
  const int w3i = (lane & 7) * 9 + (lane >> 3);
  u64 W3L[16];
  u32 W3H[16];
  #pragma unroll
  for (int e = 0; e < 16; ++e) W3L[e] = __ballot(w3[e * 72 + w3i] < 0.f);
  {
    const int hb = (lane & 7) * 9 + 8;
    const u64 h0 = __ballot(w3[((lane >> 3)    ) * 72 + hb] < 0.f);
    const u64 h1 = __ballot(w3[((lane >> 3) + 8) * 72 + hb] < 0.f);
    #pragma unroll
    for (int e = 0; e < 16; ++e)
      W3H[e] = (u32)(((e < 8 ? h0 : h1) >> (8 * (e & 7))) & 0xFFu);
  }

  // wfc1 [8][16]: memory order j*16+e == bit order. Two ballots.
  const u64 f0 = __ballot(wfc1[lane] < 0.f);
  const u64 f1 = __ballot(wfc1[64 + lane] < 0.f);
  u32 WF1[8];
  #pragma unroll
  for (int j = 0; j < 8; ++j)
    WF1[j] = (u32)(((j < 4 ? f0 : f1) >> (16 * (j & 3))) & 0xFFFFu);

  // wfc2 [1][8]
  const float vf2 = wfc2[lane < 8 ? lane : 0];
  const u32 wf2 = (u32)__ballot((lane < 8) && (vf2 < 0.f)) & 0xFFu;

  __syncthreads();  // single-wave barrier: orders LDS ballot-stores -> reads

  // ---- Eval: byte-identical to the verified R3/R4 kernel ----
  const u64* stw = st;
  const int f0i = 225 * lane;
  const int w0 = f0i >> 6;
  const int sh = f0i & 63;
  u64 Wd[5];
  #pragma unroll
  for (int i = 0; i < 5; ++i) Wd[i] = stw[w0 + i];
  u64 Bv[4];
  #pragma unroll
  for (int i = 0; i < 4; ++i)
    Bv[i] = (Wd[i] >> sh) | ((Wd[i + 1] << (63 - sh)) << 1);  // sh==0 -> 0 contribution

  // rows: rb[r] bit k = sign(x[b,0,r,k])
  u32 rb[15];
  #pragma unroll
  for (int r = 0; r < 15; ++r) {
    const int f = 15 * r, w = f >> 6, o = f & 63;
    u64 v = Bv[w] >> o;
    if (o > 49) v |= Bv[w + 1] << (64 - o);
    rb[r] = (u32)v & 0x7FFFu;
  }

  // ---- Layer 1: 4ch, 15x15 -> 7x7, 9 taps (always +-1 out) ----
  u64 a1[4] = {0, 0, 0, 0};  // bit 4*(7*oy+ox)+c, 1 = negative
  int pix = 0;
  #pragma unroll
  for (int oy = 0; oy < 7; ++oy) {
    const u32 r0 = rb[2 * oy], r1 = rb[2 * oy + 1], r2 = rb[2 * oy + 2];
    #pragma unroll
    for (int ox = 0; ox < 7; ++ox) {
      const u32 t9 = ((r0 >> (2 * ox)) & 7) | (((r1 >> (2 * ox)) & 7) << 3)
                   | (((r2 >> (2 * ox)) & 7) << 6);
      u32 nib = 0;
      nib |= (u32)(__popc(t9 ^ w1p0) >= 5) << 0;
      nib |= (u32)(__popc(t9 ^ w1p1) >= 5) << 1;
      nib |= (u32)(__popc(t9 ^ w1p2) >= 5) << 2;
      nib |= (u32)(__popc(t9 ^ w1p3) >= 5) << 3;
      a1[pix >> 4] |= (u64)nib << ((pix & 15) * 4);
      ++pix;
    }
  }

  // ---- Layer 2: 8ch, 7x7 -> 3x3, 36 taps (ternary out) ----
  u64 v2lo = 0, nz2lo = 0; u32 v2hi = 0, nz2hi = 0;  // bit 8*(3*oy+ox)+d
  #pragma unroll
  for (int oy = 0; oy < 3; ++oy) {
    #pragma unroll
    for (int ox = 0; ox < 3; ++ox) {
      u64 T = 0;
      #pragma unroll
      for (int ky = 0; ky < 3; ++ky) {
        const int p = 4 * (7 * (2 * oy + ky) + 2 * ox);
        const int w = p >> 6, o = p & 63;
        u64 v = a1[w] >> o;
        if (o > 52) v |= a1[w + 1] << (64 - o);
        T |= (v & 0xFFFull) << (12 * ky);
      }
      const int pix2 = 3 * oy + ox;
      u32 bv = 0, bz = 0;
      #pragma unroll
      for (int d = 0; d < 8; ++d) {
        const int cnt = __popcll(T ^ W2[d]);  // #neg products of 36
        bv |= (u32)(cnt > 18) << d;           // sum = 36-2cnt < 0
        bz |= (u32)(cnt != 18) << d;          // nonzero
      }
      if (pix2 < 8) { v2lo |= (u64)bv << (8 * pix2); nz2lo |= (u64)bz << (8 * pix2); }
      else          { v2hi = bv; nz2hi = bz; }
    }
  }

  // ---- Layer 3: 16ch, 3x3 -> 1x1, 72 taps, ternary in/out ----
  const int nztot = __popcll(nz2lo) + __popc(nz2hi);
  u32 s3v = 0, s3nz = 0;
  #pragma unroll
  for (int e = 0; e < 16; ++e) {
    const int cnt = __popcll(nz2lo & (v2lo ^ W3L[e])) + __popc(nz2hi & (v2hi ^ W3H[e]));
    const int s = nztot - 2 * cnt;
    s3v  |= (u32)(s < 0) << e;
    s3nz |= (u32)(s != 0) << e;
  }

  // ---- FC1: 16 -> 8, ternary ----
  const int n3 = __popc(s3nz);
  u32 hv = 0, hz = 0;
  #pragma unroll
  for (int j = 0; j < 8; ++j) {
    const int c2 = __popc(s3nz & (s3v ^ WF1[j]));
    const int s = n3 - 2 * c2;
    hv |= (u32)(s < 0) << j;
    hz |= (u32)(s != 0) << j;
  }

  // ---- FC2: 8 -> 1 (no hardtanh) ----
  const int c3 = __popc(hz & (hv ^ wf2));
  const int sfin = __popc(hz) - 2 * c3;
  out[b0 + lane] = (float)sfin;
}

extern "C" void kernel_launch(void* const* d_in, const int* in_sizes, int n_in,
                              void* d_out, int out_size, void* d_ws, size_t ws_size,
                              hipStream_t stream) {
  const float* x    = (const float*)d_in[0];
  const float* w1   = (const float*)d_in[1];
  const float* w2   = (const float*)d_in[2];
  const float* w3   = (const float*)d_in[3];
  const float* wfc1 = (const float*)d_in[4];
  const float* wfc2 = (const float*)d_in[5];
  float* out = (float*)d_out;
  const int B = in_sizes[0] / 225;  // 131072

  (void)d_ws; (void)ws_size; (void)n_in; (void)out_size;
  binnet<<<B / 64, 64, 0, stream>>>(x, w1, w2, w3, wfc1, wfc2, out);
}